// Round 11
// baseline (2307.689 us; speedup 1.0000x reference)
//
#include <hip/hip_runtime.h>
#include <hip/hip_bf16.h>

#define N_GRAPHS 64
#define TPAD 68     // padded LDS row stride (floats)
#define NT 16       // src tiles (src >> TSHIFT); tiles 13-15 empty for N=100k
#define TSHIFT 13   // 8192 nodes/tile -> 2MB of gather source per tile

// ---------------- bucket-level histogram (bucket = dst>>8, 256 nodes) ----------------

#define EBH 8192
__global__ void bucket_hist_kernel(const int* __restrict__ dst, int* __restrict__ bcnt,
                                   int E, int nbuck) {
    __shared__ int lh[512];
    const int tid = threadIdx.x;
    for (int i = tid; i < 512; i += 256) lh[i] = 0;
    __syncthreads();
    const int e0 = blockIdx.x * EBH;
    const int e1 = min(e0 + EBH, E);
    for (int e = e0 + tid; e < e1; e += 256)
        atomicAdd(&lh[((unsigned)dst[e]) >> 8], 1);
    __syncthreads();
    for (int i = tid; i < nbuck; i += 256) {
        int c = lh[i];
        if (c) atomicAdd(&bcnt[i], c);
    }
}

__global__ void bucket_scan_kernel(const int* __restrict__ bcnt, int* __restrict__ bbase,
                                   int* __restrict__ bcur, int nbuck) {
    __shared__ int sh[512];
    const int tid = threadIdx.x;
    int v = (tid < nbuck) ? bcnt[tid] : 0;
    sh[tid] = v;
    __syncthreads();
    for (int off = 1; off < 512; off <<= 1) {
        int t = (tid >= off) ? sh[tid - off] : 0;
        __syncthreads();
        sh[tid] += t;
        __syncthreads();
    }
    if (tid < nbuck) { int e = sh[tid] - v; bbase[tid] = e; bcur[tid] = e; }
    if (tid == nbuck - 1) bbase[nbuck] = sh[tid];
}

// ---------------- binned scatter: packed edge = dloc<<24 | src ----------------

#define EBC 4096
__global__ void binscatter_kernel(const int* __restrict__ src, const int* __restrict__ dst,
                                  int* __restrict__ bcur, unsigned* __restrict__ binned,
                                  int E, int nbuck) {
    __shared__ int lhist[512];
    __shared__ int lbase[512];
    const int tid = threadIdx.x;
    const int e0 = blockIdx.x * EBC;
    const int e1 = min(e0 + EBC, E);
    for (int i = tid; i < 512; i += 256) lhist[i] = 0;
    __syncthreads();
    for (int e = e0 + tid; e < e1; e += 256) atomicAdd(&lhist[((unsigned)dst[e]) >> 8], 1);
    __syncthreads();
    for (int i = tid; i < nbuck; i += 256) {
        int c = lhist[i];
        lbase[i] = (c > 0) ? atomicAdd(&bcur[i], c) : 0;
        lhist[i] = 0;
    }
    __syncthreads();
    for (int e = e0 + tid; e < e1; e += 256) {
        int d = dst[e];
        int b = ((unsigned)d) >> 8;
        int off = atomicAdd(&lhist[b], 1);
        binned[lbase[b] + off] = ((unsigned)(d & 255) << 24) | (unsigned)src[e];
    }
}

// ---------------- per-bucket build: (wave,tile,slot)-sorted col3, cnt16, wstart,
//                  degrees -> dis, Xs = dis*x ----------------
// key = (dloc>>5)*512 + tile*32 + (dloc&31);  8 waves x 32 slots per bucket

__global__ void build_sorted_kernel(const unsigned* __restrict__ binned, const int* __restrict__ bbase,
                                    const float* __restrict__ x, float* __restrict__ dis_g,
                                    float* __restrict__ Xs, int* __restrict__ col3,
                                    unsigned short* __restrict__ cnt16, int* __restrict__ wstart,
                                    int n) {
    __shared__ int ck[4096];
    __shared__ int wsum[4];
    const int b = blockIdx.x;
    const int node_base = b << 8;
    const int tid = threadIdx.x;
    for (int i = tid; i < 4096; i += 256) ck[i] = 0;
    __syncthreads();
    const int e0 = bbase[b], e1 = bbase[b + 1];
    for (int e = e0 + tid; e < e1; e += 256) {
        unsigned v = binned[e];
        int dloc = v >> 24;
        int tt = (int)((v & 0xFFFFFFu) >> TSHIFT);
        atomicAdd(&ck[(dloc >> 5) * 512 + tt * 32 + (dloc & 31)], 1);
    }
    __syncthreads();
    // degrees -> dis, Xs
    {
        int node = node_base + tid;
        if (node < n) {
            int w2 = tid >> 5, sl = tid & 31;
            int deg = 0;
            #pragma unroll
            for (int tt = 0; tt < NT; ++tt) deg += ck[w2 * 512 + tt * 32 + sl];
            float d = rsqrtf((float)deg + 1.0f);
            dis_g[node] = d;
            float4 xv = *(const float4*)&x[node * 4];
            *(float4*)&Xs[node * 4] = make_float4(d * xv.x, d * xv.y, d * xv.z, d * xv.w);
        }
    }
    // per-(wave,tile) totals
    if (tid < 128) {
        int w2 = tid >> 4, tt = tid & 15;
        int s = 0;
        #pragma unroll
        for (int sl = 0; sl < 32; ++sl) s += ck[w2 * 512 + tt * 32 + sl];
        cnt16[(size_t)(b * 8 + w2) * NT + tt] = (unsigned short)s;
    }
    __syncthreads();
    // exclusive scan of ck (4096 keys, 16/thread) -> global col3 offsets (base e0)
    const int base_i = tid * 16;
    int lsum = 0;
    #pragma unroll
    for (int j = 0; j < 16; ++j) lsum += ck[base_i + j];
    const int lane = tid & 63, wid = tid >> 6;
    int s = lsum;
    #pragma unroll
    for (int off = 1; off < 64; off <<= 1) {
        int t = __shfl_up(s, off);
        if (lane >= off) s += t;
    }
    if (lane == 63) wsum[wid] = s;
    __syncthreads();
    int woff = 0;
    for (int w = 0; w < wid; ++w) woff += wsum[w];
    int run = e0 + woff + s - lsum;
    #pragma unroll
    for (int j = 0; j < 16; ++j) { int c = ck[base_i + j]; ck[base_i + j] = run; run += c; }
    __syncthreads();
    if (tid < 8) wstart[b * 8 + tid] = ck[tid * 512];
    __syncthreads();
    // scatter (keep packed dloc<<24|src; agg uses slot = (v>>24)&31)
    for (int e = e0 + tid; e < e1; e += 256) {
        unsigned v = binned[e];
        int dloc = v >> 24;
        int tt = (int)((v & 0xFFFFFFu) >> TSHIFT);
        int p = atomicAdd(&ck[(dloc >> 5) * 512 + tt * 32 + (dloc & 31)], 1);
        col3[p] = (int)v;
    }
}

// ---------------- phase-aligned aggregation, wave-private LDS accumulators ----------------
// 782 blocks x 4 waves, all resident. Wave owns 32 nodes: acc[slot][f] in wave-private LDS.
// Edge broadcast: plain VECTOR load at wave-uniform address (no shfl, no readfirstlane ->
// no scalar-load lgkmcnt drain). Accumulate: LDS atomicAdd (ds_add_f32, 1 DS op).
// EPG=64/F edges per instruction group. Chip-wide tile phases align -> 2MB L2 slice/phase.

template <int F, bool RELU, bool BIAS, int UNR>
__global__ __launch_bounds__(256, 4)
void agg_phase_kernel(const float* __restrict__ t, const int* __restrict__ col3,
                      const unsigned short* __restrict__ cnt16, const int* __restrict__ wstart,
                      const float* __restrict__ dis, const float* __restrict__ bias,
                      float* __restrict__ out, int n, int nwave) {
    constexpr int EPG = 64 / F;
    __shared__ float accs[4][32 * F];
    const int tid = threadIdx.x;
    const int wl = tid >> 6, lane = tid & 63;
    float* acc = accs[wl];
    for (int i = lane; i < 32 * F; i += 64) acc[i] = 0.0f;
    const int gw = blockIdx.x * 4 + wl;
    if (gw >= nwave) return;
    const int grp = lane / F;        // 0..EPG-1
    const int fl = lane & (F - 1);
    int cur = wstart[gw];            // stays in VGPR (divergent-looking)
    for (int tp = 0; tp < NT; ++tp) {
        const int cnt = (int)cnt16[(size_t)gw * NT + tp];
        constexpr int STEP = UNR * EPG;
        const int jm = (cnt / STEP) * STEP;
        int j = 0;
        for (; j < jm; j += STEP) {
            #pragma unroll
            for (int u = 0; u < UNR; ++u) {
                const unsigned v = (unsigned)col3[cur + j + u * EPG + grp];
                const float xv = t[(size_t)(v & 0xFFFFFFu) * F + fl];
                atomicAdd(&acc[((v >> 24) & 31) * F + fl], xv);
            }
        }
        for (; j + grp < cnt; j += EPG) {
            const unsigned v = (unsigned)col3[cur + j + grp];
            const float xv = t[(size_t)(v & 0xFFFFFFu) * F + fl];
            atomicAdd(&acc[((v >> 24) & 31) * F + fl], xv);
        }
        cur += cnt;
    }
    // epilogue: out = [relu]( dis_i * (acc + t_self) + [bias] )
    const int nodeb = gw * 32;
    const float bv = BIAS ? bias[fl] : 0.0f;
    for (int k = 0; k < 32; ++k) {
        int i = nodeb + k;
        if (i < n && lane < F) {
            float d = dis[i];
            float r = d * (acc[k * F + fl] + t[(size_t)i * F + fl]) + bv;
            if (RELU) r = fmaxf(r, 0.0f);
            out[(size_t)i * F + fl] = r;
        }
    }
}

// ---------------- fused layer-1 transform + layer-2 pre-transform ----------------
// T[i] = dis[i] * ( relu(aggX[i] @ W1 + b1) @ W2 )

__global__ void fused_l1_kernel(const float* __restrict__ aggX, const float* __restrict__ W1,
                                const float* __restrict__ b1, const float* __restrict__ W2,
                                const float* __restrict__ dis, float* __restrict__ t, int n) {
    __shared__ float W1s[256];
    __shared__ float b1s[64];
    __shared__ float Wt[64 * TPAD];
    __shared__ float Hs[64 * TPAD];
    const int tid = threadIdx.x;
    const int base = blockIdx.x * 64;
    if (tid < 256) W1s[tid] = W1[tid];
    if (tid < 64) b1s[tid] = b1[tid];
    for (int idx = tid; idx < 4096; idx += 256) {
        int k = idx >> 6, f = idx & 63;
        Wt[f * TPAD + k] = W2[idx];
    }
    __syncthreads();
    for (int idx = tid; idx < 4096; idx += 256) {
        int nn = idx >> 6, k = idx & 63;
        int node = base + nn;
        float v = 0.0f;
        if (node < n) {
            float4 a = *(const float4*)&aggX[node * 4];
            v = fmaxf(a.x * W1s[k] + a.y * W1s[64 + k] + a.z * W1s[128 + k] + a.w * W1s[192 + k]
                      + b1s[k], 0.0f);
        }
        Hs[nn * TPAD + k] = v;
    }
    __syncthreads();
    const int tf = tid & 15;
    const int tn = tid >> 4;
    float acc[4][4] = {};
    for (int k = 0; k < 64; k += 4) {
        float4 w4[4], h4[4];
        #pragma unroll
        for (int ff = 0; ff < 4; ++ff) w4[ff] = *(const float4*)&Wt[(tf * 4 + ff) * TPAD + k];
        #pragma unroll
        for (int nn = 0; nn < 4; ++nn) h4[nn] = *(const float4*)&Hs[(tn * 4 + nn) * TPAD + k];
        #pragma unroll
        for (int nn = 0; nn < 4; ++nn)
            #pragma unroll
            for (int ff = 0; ff < 4; ++ff)
                acc[nn][ff] += h4[nn].x * w4[ff].x + h4[nn].y * w4[ff].y +
                               h4[nn].z * w4[ff].z + h4[nn].w * w4[ff].w;
    }
    #pragma unroll
    for (int nn = 0; nn < 4; ++nn) {
        int node = base + tn * 4 + nn;
        if (node < n) {
            float d = dis[node];
            float4 o = make_float4(d * acc[nn][0], d * acc[nn][1], d * acc[nn][2], d * acc[nn][3]);
            *(float4*)&t[node * 64 + tf * 4] = o;
        }
    }
}

// ---------------- W3 transform: T32[i] = dis[i] * (H[i] @ W3) ----------------

__global__ void transform64_32_kernel(const float* __restrict__ h, const float* __restrict__ W,
                                      const float* __restrict__ dis, float* __restrict__ t, int n) {
    __shared__ float Wt[32 * TPAD];
    __shared__ float Hs[128 * TPAD];
    const int tid = threadIdx.x;
    const int base = blockIdx.x * 128;
    for (int idx = tid; idx < 2048; idx += 256) {
        int k = idx >> 5, f = idx & 31;
        Wt[f * TPAD + k] = W[idx];
    }
    for (int idx = tid; idx < 8192; idx += 256) {
        int nn = idx >> 6, k = idx & 63;
        int node = base + nn;
        Hs[nn * TPAD + k] = (node < n) ? h[node * 64 + k] : 0.0f;
    }
    __syncthreads();
    const int tf = tid & 7;
    const int tn = tid >> 3;
    float acc[4][4] = {};
    for (int k = 0; k < 64; k += 4) {
        float4 w4[4], h4[4];
        #pragma unroll
        for (int ff = 0; ff < 4; ++ff) w4[ff] = *(const float4*)&Wt[(tf * 4 + ff) * TPAD + k];
        #pragma unroll
        for (int nn = 0; nn < 4; ++nn) h4[nn] = *(const float4*)&Hs[(tn * 4 + nn) * TPAD + k];
        #pragma unroll
        for (int nn = 0; nn < 4; ++nn)
            #pragma unroll
            for (int ff = 0; ff < 4; ++ff)
                acc[nn][ff] += h4[nn].x * w4[ff].x + h4[nn].y * w4[ff].y +
                               h4[nn].z * w4[ff].z + h4[nn].w * w4[ff].w;
    }
    #pragma unroll
    for (int nn = 0; nn < 4; ++nn) {
        int node = base + tn * 4 + nn;
        if (node < n) {
            float d = dis[node];
            float4 o = make_float4(d * acc[nn][0], d * acc[nn][1], d * acc[nn][2], d * acc[nn][3]);
            *(float4*)&t[node * 32 + tf * 4] = o;
        }
    }
}

// ---------------- readout ----------------

__device__ __forceinline__ unsigned mapf(float v) {
    unsigned u = __float_as_uint(v);
    return u ^ ((u & 0x80000000u) ? 0xFFFFFFFFu : 0x80000000u);
}

#define MAPPED_NEG_INF 0x007FFFFFu

__global__ void init_readout_kernel(float* __restrict__ gsum, unsigned* __restrict__ gmax,
                                    int* __restrict__ gcnt) {
    int idx = blockIdx.x * blockDim.x + threadIdx.x;
    if (idx < N_GRAPHS * 32) { gsum[idx] = 0.0f; gmax[idx] = MAPPED_NEG_INF; }
    if (idx < N_GRAPHS) gcnt[idx] = 0;
}

#define R_CHUNK 512
__global__ void readout_kernel(const float* __restrict__ emb, const int* __restrict__ batch,
                               float* __restrict__ gsum, unsigned* __restrict__ gmax,
                               int* __restrict__ gcnt, int n) {
    __shared__ float ssum[N_GRAPHS * 32];
    __shared__ unsigned smax[N_GRAPHS * 32];
    __shared__ int scnt[N_GRAPHS];
    const int tid = threadIdx.x;
    for (int idx = tid; idx < N_GRAPHS * 32; idx += 256) { ssum[idx] = 0.0f; smax[idx] = MAPPED_NEG_INF; }
    if (tid < N_GRAPHS) scnt[tid] = 0;
    __syncthreads();
    const int lane = tid & 31, grp = tid >> 5;
    const int start = blockIdx.x * R_CHUNK;
    const int end = min(start + R_CHUNK, n);
    for (int i = start + grp; i < end; i += 8) {
        int g = batch[i];
        float v = emb[i * 32 + lane];
        atomicAdd(&ssum[g * 32 + lane], v);
        atomicMax(&smax[g * 32 + lane], mapf(v));
        if (lane == 0) atomicAdd(&scnt[g], 1);
    }
    __syncthreads();
    for (int idx = tid; idx < N_GRAPHS * 32; idx += 256) {
        int g = idx >> 5;
        if (scnt[g] > 0) {
            atomicAdd(&gsum[idx], ssum[idx]);
            atomicMax(&gmax[idx], smax[idx]);
        }
    }
    if (tid < N_GRAPHS && scnt[tid] > 0) atomicAdd(&gcnt[tid], scnt[tid]);
}

__global__ void finalize_kernel(const float* __restrict__ gsum, const unsigned* __restrict__ gmax,
                                const int* __restrict__ gcnt, float* __restrict__ out) {
    int idx = blockIdx.x * blockDim.x + threadIdx.x;
    if (idx >= N_GRAPHS * 32) return;
    int g = idx >> 5, f = idx & 31;
    float c = fmaxf((float)gcnt[g], 1.0f);
    out[g * 64 + f] = gsum[idx] / c;
    unsigned u = gmax[idx];
    unsigned bits = (u & 0x80000000u) ? (u ^ 0x80000000u) : ~u;
    out[g * 64 + 32 + f] = __uint_as_float(bits);
}

// ---------------- launch ----------------

extern "C" void kernel_launch(void* const* d_in, const int* in_sizes, int n_in,
                              void* d_out, int out_size, void* d_ws, size_t ws_size,
                              hipStream_t stream) {
    const float* x  = (const float*)d_in[0];
    const float* W1 = (const float*)d_in[1];
    const float* b1 = (const float*)d_in[2];
    const float* W2 = (const float*)d_in[3];
    const float* b2 = (const float*)d_in[4];
    const float* W3 = (const float*)d_in[5];
    const float* b3 = (const float*)d_in[6];
    const int* edge_index = (const int*)d_in[7];
    const int* batch = (const int*)d_in[8];
    float* out = (float*)d_out;

    const int N = in_sizes[0] / 4;
    const int E = in_sizes[7] / 2;
    const int* src = edge_index;
    const int* dst = edge_index + E;
    const int nbuck = (N + 255) >> 8;        // 391
    const int nwave = nbuck * 8;             // 3128 (wave = 32 nodes)
    const int gagg = (nwave + 3) / 4;        // 782 blocks, all resident

    // workspace carve-up (256B aligned)
    char* p = (char*)d_ws;
    auto alloc = [&](size_t bytes) { void* r = (void*)p; p += (bytes + 255) & ~(size_t)255; return r; };
    float*          dis    = (float*)alloc((size_t)N * 4);
    int*            col3   = (int*)alloc((size_t)E * 4);
    unsigned short* cnt16  = (unsigned short*)alloc((size_t)nwave * NT * 2);
    int*            wstart = (int*)alloc((size_t)nwave * 4);
    float*          T      = (float*)alloc((size_t)N * 64 * 4);
    float*          H      = (float*)alloc((size_t)N * 64 * 4);
    float*          T32    = (float*)alloc((size_t)N * 32 * 4);
    int*            bcnt   = (int*)alloc((size_t)512 * 4);
    int*            bbase  = (int*)alloc((size_t)513 * 4);
    int*            bcur   = (int*)alloc((size_t)512 * 4);
    float*          gsum   = (float*)alloc((size_t)N_GRAPHS * 32 * 4);
    unsigned*       gmax   = (unsigned*)alloc((size_t)N_GRAPHS * 32 * 4);
    int*            gcnt   = (int*)alloc((size_t)N_GRAPHS * 4);
    // aliases (lifetimes disjoint, stream-ordered):
    unsigned* binned = (unsigned*)T;           // consumed by build before fused_l1 writes T
    float*    Xs     = H;                      // dead before agg<64> writes H
    float*    aggX   = H + (size_t)N * 4;      // dead before agg<64> writes H
    float*    H32    = T;                      // written after T dead (post transform64_32)
    (void)ws_size; (void)n_in; (void)out_size;

    // CSR build: bucket-binned scatter, then per-bucket (wave,tile,slot) sort
    hipMemsetAsync(bcnt, 0, 512 * 4, stream);
    bucket_hist_kernel<<<(E + EBH - 1) / EBH, 256, 0, stream>>>(dst, bcnt, E, nbuck);
    bucket_scan_kernel<<<1, 512, 0, stream>>>(bcnt, bbase, bcur, nbuck);
    binscatter_kernel<<<(E + EBC - 1) / EBC, 256, 0, stream>>>(src, dst, bcur, binned, E, nbuck);
    build_sorted_kernel<<<nbuck, 256, 0, stream>>>(binned, bbase, x, dis, Xs, col3, cnt16, wstart, N);

    // layer 1: phase-aligned aggregate Xs (4-dim) -> aggX = dis*(sum+self), then fused transform -> T
    agg_phase_kernel<4, false, false, 2><<<gagg, 256, 0, stream>>>(Xs, col3, cnt16, wstart, dis, b1, aggX, N, nwave);
    fused_l1_kernel<<<(N + 63) / 64, 256, 0, stream>>>(aggX, W1, b1, W2, dis, T, N);
    // layer 2: phase-aligned aggregate T (64-dim) -> H = relu(dis*(sum+self)+b2)
    agg_phase_kernel<64, true, true, 8><<<gagg, 256, 0, stream>>>(T, col3, cnt16, wstart, dis, b2, H, N, nwave);
    // W3: T32 = dis * (H @ W3)
    transform64_32_kernel<<<(N + 127) / 128, 256, 0, stream>>>(H, W3, dis, T32, N);
    // layer 3: phase-aligned aggregate T32 (32-dim) -> H32 = dis*(sum+self)+b3
    agg_phase_kernel<32, false, true, 4><<<gagg, 256, 0, stream>>>(T32, col3, cnt16, wstart, dis, b3, H32, N, nwave);

    // readout
    init_readout_kernel<<<(N_GRAPHS * 32 + 255) / 256, 256, 0, stream>>>(gsum, gmax, gcnt);
    readout_kernel<<<(N + R_CHUNK - 1) / R_CHUNK, 256, 0, stream>>>(H32, batch, gsum, gmax, gcnt, N);
    finalize_kernel<<<(N_GRAPHS * 32 + 255) / 256, 256, 0, stream>>>(gsum, gmax, gcnt, out);
}

// Round 15
// 389.031 us; speedup vs baseline: 5.9319x; 5.9319x over previous
//
#include <hip/hip_runtime.h>
#include <hip/hip_bf16.h>

#define N_GRAPHS 64
#define TPAD 68   // padded LDS row stride (floats)

// ---------------- bucket-level histogram (bucket = dst>>8) ----------------

#define EBH 8192
__global__ void bucket_hist_kernel(const int* __restrict__ dst, int* __restrict__ bcnt,
                                   int E, int nbuck) {
    __shared__ int lh[512];
    const int tid = threadIdx.x;
    for (int i = tid; i < 512; i += 256) lh[i] = 0;
    __syncthreads();
    const int e0 = blockIdx.x * EBH;
    const int e1 = min(e0 + EBH, E);
    for (int e = e0 + tid; e < e1; e += 256)
        atomicAdd(&lh[((unsigned)dst[e]) >> 8], 1);
    __syncthreads();
    for (int i = tid; i < nbuck; i += 256) {
        int c = lh[i];
        if (c) atomicAdd(&bcnt[i], c);
    }
}

// exclusive scan of bucket counts (nbuck <= 512), seed bucket cursors
__global__ void bucket_scan_kernel(const int* __restrict__ bcnt, int* __restrict__ bbase,
                                   int* __restrict__ bcur, int nbuck) {
    __shared__ int sh[512];
    const int tid = threadIdx.x;
    int v = (tid < nbuck) ? bcnt[tid] : 0;
    sh[tid] = v;
    __syncthreads();
    for (int off = 1; off < 512; off <<= 1) {
        int t = (tid >= off) ? sh[tid - off] : 0;
        __syncthreads();
        sh[tid] += t;
        __syncthreads();
    }
    if (tid < nbuck) { int e = sh[tid] - v; bbase[tid] = e; bcur[tid] = e; }
    if (tid == nbuck - 1) bbase[nbuck] = sh[tid];
}

// ---------------- binned scatter: packed edge = (dst&255)<<24 | src ----------------

#define EBC 4096
__global__ void binscatter_kernel(const int* __restrict__ src, const int* __restrict__ dst,
                                  int* __restrict__ bcur, unsigned* __restrict__ binned,
                                  int E, int nbuck) {
    __shared__ int lhist[512];
    __shared__ int lbase[512];
    const int tid = threadIdx.x;
    const int e0 = blockIdx.x * EBC;
    const int e1 = min(e0 + EBC, E);
    for (int i = tid; i < 512; i += 256) lhist[i] = 0;
    __syncthreads();
    for (int e = e0 + tid; e < e1; e += 256) atomicAdd(&lhist[((unsigned)dst[e]) >> 8], 1);
    __syncthreads();
    for (int i = tid; i < nbuck; i += 256) {
        int c = lhist[i];
        lbase[i] = (c > 0) ? atomicAdd(&bcur[i], c) : 0;
        lhist[i] = 0;
    }
    __syncthreads();
    for (int e = e0 + tid; e < e1; e += 256) {
        int d = dst[e];
        int b = ((unsigned)d) >> 8;
        int off = atomicAdd(&lhist[b], 1);
        binned[lbase[b] + off] = ((unsigned)(d & 255) << 24) | (unsigned)src[e];
    }
}

// ---------------- per-bucket: node degrees, rs, dis, Xs=dis*x, CSR scatter ----------------

__global__ void build_bucket_kernel(const unsigned* __restrict__ binned, const int* __restrict__ bbase,
                                    const float* __restrict__ x, int* __restrict__ rs,
                                    float* __restrict__ dis_g, float* __restrict__ Xs,
                                    int* __restrict__ col, int n) {
    __shared__ int cnt[256];
    __shared__ int lcur[256];
    __shared__ int wsum[4];
    const int b = blockIdx.x;
    const int node_base = b << 8;
    const int nb = min(256, n - node_base);
    const int tid = threadIdx.x;
    cnt[tid] = 0;
    __syncthreads();
    const int e0 = bbase[b], e1 = bbase[b + 1];
    for (int e = e0 + tid; e < e1; e += 256)
        atomicAdd(&cnt[binned[e] >> 24], 1);
    __syncthreads();
    const int deg = cnt[tid];
    // exclusive scan over 256 entries
    const int lane = tid & 63, wid = tid >> 6;
    int s = deg;
    #pragma unroll
    for (int off = 1; off < 64; off <<= 1) {
        int t = __shfl_up(s, off);
        if (lane >= off) s += t;
    }
    if (lane == 63) wsum[wid] = s;
    __syncthreads();
    int woff = 0;
    for (int w = 0; w < wid; ++w) woff += wsum[w];
    const int excl = woff + s - deg;
    if (tid < nb) {
        int node = node_base + tid;
        rs[node] = e0 + excl;
        float d = rsqrtf((float)deg + 1.0f);
        dis_g[node] = d;
        float4 xv = *(const float4*)&x[node * 4];
        *(float4*)&Xs[node * 4] = make_float4(d * xv.x, d * xv.y, d * xv.z, d * xv.w);
    }
    lcur[tid] = e0 + excl;
    if (tid == 0 && node_base + nb == n) rs[n] = e1;
    __syncthreads();
    for (int e = e0 + tid; e < e1; e += 256) {
        unsigned v = binned[e];
        int p = atomicAdd(&lcur[v >> 24], 1);
        col[p] = (int)(v & 0xFFFFFFu);
    }
}

// ---------------- layer 1: aggregate x (4-dim) ----------------

__global__ void agg4_kernel(const float* __restrict__ Xs, const int* __restrict__ col,
                            const int* __restrict__ rs, const float* __restrict__ dis,
                            float* __restrict__ aggX, int n) {
    int i = blockIdx.x * blockDim.x + threadIdx.x;
    if (i >= n) return;
    int e = rs[i];
    const int end = rs[i + 1];
    float4 a0 = make_float4(0, 0, 0, 0), a1 = make_float4(0, 0, 0, 0);
    for (; e + 2 <= end; e += 2) {
        int s0 = col[e], s1 = col[e + 1];
        float4 v0 = *(const float4*)&Xs[s0 * 4];
        float4 v1 = *(const float4*)&Xs[s1 * 4];
        a0.x += v0.x; a0.y += v0.y; a0.z += v0.z; a0.w += v0.w;
        a1.x += v1.x; a1.y += v1.y; a1.z += v1.z; a1.w += v1.w;
    }
    if (e < end) {
        float4 v = *(const float4*)&Xs[col[e] * 4];
        a0.x += v.x; a0.y += v.y; a0.z += v.z; a0.w += v.w;
    }
    float4 self = *(const float4*)&Xs[i * 4];
    float d = dis[i];
    float4 r = make_float4(d * (a0.x + a1.x + self.x), d * (a0.y + a1.y + self.y),
                           d * (a0.z + a1.z + self.z), d * (a0.w + a1.w + self.w));
    *(float4*)&aggX[i * 4] = r;
}

// ---------------- fused layer-1 transform + layer-2 pre-transform ----------------
// T[i] = dis[i] * ( relu(aggX[i] @ W1 + b1) @ W2 )

__global__ void fused_l1_kernel(const float* __restrict__ aggX, const float* __restrict__ W1,
                                const float* __restrict__ b1, const float* __restrict__ W2,
                                const float* __restrict__ dis, float* __restrict__ t, int n) {
    __shared__ float W1s[256];
    __shared__ float b1s[64];
    __shared__ float Wt[64 * TPAD];
    __shared__ float Hs[64 * TPAD];
    const int tid = threadIdx.x;
    const int base = blockIdx.x * 64;
    if (tid < 256) W1s[tid] = W1[tid];
    if (tid < 64) b1s[tid] = b1[tid];
    for (int idx = tid; idx < 4096; idx += 256) {
        int k = idx >> 6, f = idx & 63;
        Wt[f * TPAD + k] = W2[idx];
    }
    __syncthreads();
    for (int idx = tid; idx < 4096; idx += 256) {
        int nn = idx >> 6, k = idx & 63;
        int node = base + nn;
        float v = 0.0f;
        if (node < n) {
            float4 a = *(const float4*)&aggX[node * 4];
            v = fmaxf(a.x * W1s[k] + a.y * W1s[64 + k] + a.z * W1s[128 + k] + a.w * W1s[192 + k]
                      + b1s[k], 0.0f);
        }
        Hs[nn * TPAD + k] = v;
    }
    __syncthreads();
    const int tf = tid & 15;
    const int tn = tid >> 4;
    float acc[4][4] = {};
    for (int k = 0; k < 64; k += 4) {
        float4 w4[4], h4[4];
        #pragma unroll
        for (int ff = 0; ff < 4; ++ff) w4[ff] = *(const float4*)&Wt[(tf * 4 + ff) * TPAD + k];
        #pragma unroll
        for (int nn = 0; nn < 4; ++nn) h4[nn] = *(const float4*)&Hs[(tn * 4 + nn) * TPAD + k];
        #pragma unroll
        for (int nn = 0; nn < 4; ++nn)
            #pragma unroll
            for (int ff = 0; ff < 4; ++ff)
                acc[nn][ff] += h4[nn].x * w4[ff].x + h4[nn].y * w4[ff].y +
                               h4[nn].z * w4[ff].z + h4[nn].w * w4[ff].w;
    }
    #pragma unroll
    for (int nn = 0; nn < 4; ++nn) {
        int node = base + tn * 4 + nn;
        if (node < n) {
            float d = dis[node];
            float4 o = make_float4(d * acc[nn][0], d * acc[nn][1], d * acc[nn][2], d * acc[nn][3]);
            *(float4*)&t[node * 64 + tf * 4] = o;
        }
    }
}

// ---------------- W3 transform: T32[i] = dis[i] * (H[i] @ W3) ----------------

__global__ void transform64_32_kernel(const float* __restrict__ h, const float* __restrict__ W,
                                      const float* __restrict__ dis, float* __restrict__ t, int n) {
    __shared__ float Wt[32 * TPAD];
    __shared__ float Hs[128 * TPAD];
    const int tid = threadIdx.x;
    const int base = blockIdx.x * 128;
    for (int idx = tid; idx < 2048; idx += 256) {
        int k = idx >> 5, f = idx & 31;
        Wt[f * TPAD + k] = W[idx];
    }
    for (int idx = tid; idx < 8192; idx += 256) {
        int nn = idx >> 6, k = idx & 63;
        int node = base + nn;
        Hs[nn * TPAD + k] = (node < n) ? h[node * 64 + k] : 0.0f;
    }
    __syncthreads();
    const int tf = tid & 7;
    const int tn = tid >> 3;
    float acc[4][4] = {};
    for (int k = 0; k < 64; k += 4) {
        float4 w4[4], h4[4];
        #pragma unroll
        for (int ff = 0; ff < 4; ++ff) w4[ff] = *(const float4*)&Wt[(tf * 4 + ff) * TPAD + k];
        #pragma unroll
        for (int nn = 0; nn < 4; ++nn) h4[nn] = *(const float4*)&Hs[(tn * 4 + nn) * TPAD + k];
        #pragma unroll
        for (int nn = 0; nn < 4; ++nn)
            #pragma unroll
            for (int ff = 0; ff < 4; ++ff)
                acc[nn][ff] += h4[nn].x * w4[ff].x + h4[nn].y * w4[ff].y +
                               h4[nn].z * w4[ff].z + h4[nn].w * w4[ff].w;
    }
    #pragma unroll
    for (int nn = 0; nn < 4; ++nn) {
        int node = base + tn * 4 + nn;
        if (node < n) {
            float d = dis[node];
            float4 o = make_float4(d * acc[nn][0], d * acc[nn][1], d * acc[nn][2], d * acc[nn][3]);
            *(float4*)&t[node * 32 + tf * 4] = o;
        }
    }
}

// ---------------- aggregation (flat gather over CSR, t pre-scaled by dis) ----------------

template <int F, bool RELU>
__global__ void aggregate_kernel(const float* __restrict__ t, const int* __restrict__ col,
                                 const int* __restrict__ rs, const float* __restrict__ dis,
                                 const float* __restrict__ b, float* __restrict__ out, int n) {
    int gid = blockIdx.x * blockDim.x + threadIdx.x;
    int i, f;
    if (F == 64) { i = gid >> 6; f = threadIdx.x & 63; }
    else         { i = gid >> 5; f = threadIdx.x & 31; }
    if (i >= n) return;
    float acc0 = 0.0f, acc1 = 0.0f;
    int e = rs[i];
    const int end = rs[i + 1];
    for (; e + 8 <= end; e += 8) {
        int s0 = col[e],     s1 = col[e + 1], s2 = col[e + 2], s3 = col[e + 3];
        int s4 = col[e + 4], s5 = col[e + 5], s6 = col[e + 6], s7 = col[e + 7];
        float v0 = t[s0 * F + f], v1 = t[s1 * F + f], v2 = t[s2 * F + f], v3 = t[s3 * F + f];
        float v4 = t[s4 * F + f], v5 = t[s5 * F + f], v6 = t[s6 * F + f], v7 = t[s7 * F + f];
        acc0 += v0; acc1 += v1; acc0 += v2; acc1 += v3;
        acc0 += v4; acc1 += v5; acc0 += v6; acc1 += v7;
    }
    for (; e < end; ++e) acc0 += t[col[e] * F + f];
    float r = dis[i] * (acc0 + acc1 + t[i * F + f]) + b[f];
    if (RELU) r = fmaxf(r, 0.0f);
    out[i * F + f] = r;
}

// ---------------- readout ----------------

__device__ __forceinline__ unsigned mapf(float v) {
    unsigned u = __float_as_uint(v);
    return u ^ ((u & 0x80000000u) ? 0xFFFFFFFFu : 0x80000000u);
}

#define MAPPED_NEG_INF 0x007FFFFFu

__global__ void init_readout_kernel(float* __restrict__ gsum, unsigned* __restrict__ gmax,
                                    int* __restrict__ gcnt) {
    int idx = blockIdx.x * blockDim.x + threadIdx.x;
    if (idx < N_GRAPHS * 32) { gsum[idx] = 0.0f; gmax[idx] = MAPPED_NEG_INF; }
    if (idx < N_GRAPHS) gcnt[idx] = 0;
}

#define R_CHUNK 512
__global__ void readout_kernel(const float* __restrict__ emb, const int* __restrict__ batch,
                               float* __restrict__ gsum, unsigned* __restrict__ gmax,
                               int* __restrict__ gcnt, int n) {
    __shared__ float ssum[N_GRAPHS * 32];
    __shared__ unsigned smax[N_GRAPHS * 32];
    __shared__ int scnt[N_GRAPHS];
    const int tid = threadIdx.x;
    for (int idx = tid; idx < N_GRAPHS * 32; idx += 256) { ssum[idx] = 0.0f; smax[idx] = MAPPED_NEG_INF; }
    if (tid < N_GRAPHS) scnt[tid] = 0;
    __syncthreads();
    const int lane = tid & 31, grp = tid >> 5;
    const int start = blockIdx.x * R_CHUNK;
    const int end = min(start + R_CHUNK, n);
    for (int i = start + grp; i < end; i += 8) {
        int g = batch[i];
        float v = emb[i * 32 + lane];
        atomicAdd(&ssum[g * 32 + lane], v);
        atomicMax(&smax[g * 32 + lane], mapf(v));
        if (lane == 0) atomicAdd(&scnt[g], 1);
    }
    __syncthreads();
    for (int idx = tid; idx < N_GRAPHS * 32; idx += 256) {
        int g = idx >> 5;
        if (scnt[g] > 0) {
            atomicAdd(&gsum[idx], ssum[idx]);
            atomicMax(&gmax[idx], smax[idx]);
        }
    }
    if (tid < N_GRAPHS && scnt[tid] > 0) atomicAdd(&gcnt[tid], scnt[tid]);
}

__global__ void finalize_kernel(const float* __restrict__ gsum, const unsigned* __restrict__ gmax,
                                const int* __restrict__ gcnt, float* __restrict__ out) {
    int idx = blockIdx.x * blockDim.x + threadIdx.x;
    if (idx >= N_GRAPHS * 32) return;
    int g = idx >> 5, f = idx & 31;
    float c = fmaxf((float)gcnt[g], 1.0f);
    out[g * 64 + f] = gsum[idx] / c;
    unsigned u = gmax[idx];
    unsigned bits = (u & 0x80000000u) ? (u ^ 0x80000000u) : ~u;
    out[g * 64 + 32 + f] = __uint_as_float(bits);
}

// ---------------- launch ----------------

extern "C" void kernel_launch(void* const* d_in, const int* in_sizes, int n_in,
                              void* d_out, int out_size, void* d_ws, size_t ws_size,
                              hipStream_t stream) {
    const float* x  = (const float*)d_in[0];
    const float* W1 = (const float*)d_in[1];
    const float* b1 = (const float*)d_in[2];
    const float* W2 = (const float*)d_in[3];
    const float* b2 = (const float*)d_in[4];
    const float* W3 = (const float*)d_in[5];
    const float* b3 = (const float*)d_in[6];
    const int* edge_index = (const int*)d_in[7];
    const int* batch = (const int*)d_in[8];
    float* out = (float*)d_out;

    const int N = in_sizes[0] / 4;
    const int E = in_sizes[7] / 2;
    const int* src = edge_index;
    const int* dst = edge_index + E;
    const int nbuck = (N + 255) >> 8;    // 391

    // workspace carve-up (256B aligned)
    char* p = (char*)d_ws;
    auto alloc = [&](size_t bytes) { void* r = (void*)p; p += (bytes + 255) & ~(size_t)255; return r; };
    int*      rs   = (int*)alloc((size_t)(N + 1) * 4);
    float*    dis  = (float*)alloc((size_t)N * 4);
    int*      col  = (int*)alloc((size_t)E * 4);
    float*    Xs   = (float*)alloc((size_t)N * 4 * 4);
    float*    aggX = (float*)alloc((size_t)N * 4 * 4);
    float*    T    = (float*)alloc((size_t)N * 64 * 4);   // aliases: binned (E ints), later H32
    float*    H    = (float*)alloc((size_t)N * 64 * 4);
    float*    T32  = (float*)alloc((size_t)N * 32 * 4);
    int*      bcnt = (int*)alloc((size_t)512 * 4);
    int*      bbase= (int*)alloc((size_t)513 * 4);
    int*      bcur = (int*)alloc((size_t)512 * 4);
    float*    gsum = (float*)alloc((size_t)N_GRAPHS * 32 * 4);
    unsigned* gmax = (unsigned*)alloc((size_t)N_GRAPHS * 32 * 4);
    int*      gcnt = (int*)alloc((size_t)N_GRAPHS * 4);
    unsigned* binned = (unsigned*)T;   // consumed by build_bucket before fused_l1 writes T
    float*    H32    = T;              // written by agg32 after T is dead
    (void)ws_size; (void)n_in; (void)out_size;

    const int gN = (N + 255) / 256;

    // CSR build (binned two-level sort)
    hipMemsetAsync(bcnt, 0, 512 * 4, stream);
    bucket_hist_kernel<<<(E + EBH - 1) / EBH, 256, 0, stream>>>(dst, bcnt, E, nbuck);
    bucket_scan_kernel<<<1, 512, 0, stream>>>(bcnt, bbase, bcur, nbuck);
    binscatter_kernel<<<(E + EBC - 1) / EBC, 256, 0, stream>>>(src, dst, bcur, binned, E, nbuck);
    build_bucket_kernel<<<nbuck, 256, 0, stream>>>(binned, bbase, x, rs, dis, Xs, col, N);

    // layer 1: aggregate(4) then fused (W1,relu,b1,W2,dis) transform -> T
    agg4_kernel<<<gN, 256, 0, stream>>>(Xs, col, rs, dis, aggX, N);
    fused_l1_kernel<<<(N + 63) / 64, 256, 0, stream>>>(aggX, W1, b1, W2, dis, T, N);
    // layer 2: flat gather aggregate -> H = relu(dis*(sum+self)+b2)
    aggregate_kernel<64, true><<<(N * 64 + 255) / 256, 256, 0, stream>>>(T, col, rs, dis, b2, H, N);
    // W3: T32 = dis * (H @ W3)
    transform64_32_kernel<<<(N + 127) / 128, 256, 0, stream>>>(H, W3, dis, T32, N);
    // layer 3: flat gather aggregate -> H32 = dis*(sum+self)+b3
    aggregate_kernel<32, false><<<(N * 32 + 255) / 256, 256, 0, stream>>>(T32, col, rs, dis, b3, H32, N);

    // readout
    init_readout_kernel<<<(N_GRAPHS * 32 + 255) / 256, 256, 0, stream>>>(gsum, gmax, gcnt);
    readout_kernel<<<(N + R_CHUNK - 1) / R_CHUNK, 256, 0, stream>>>(H32, batch, gsum, gmax, gcnt, N);
    finalize_kernel<<<(N_GRAPHS * 32 + 255) / 256, 256, 0, stream>>>(gsum, gmax, gcnt, out);
}